// Round 3
// baseline (466.546 us; speedup 1.0000x reference)
//
#include <hip/hip_runtime.h>
#include <hip/hip_bf16.h>

// Problem constants
#define HDIM   2880
#define NH     64
#define NKV    8
#define DHEAD  64
#define GQ     (NH / NKV)     // 8
#define WIN    128
#define NTOK   1024
#define QKV_N  ((NH + 2 * NKV) * DHEAD)   // 5120
#define QCOLS  (NH * DHEAD)               // 4096
#define KOFF   QCOLS                      // 4096
#define VOFF   (QCOLS + NKV * DHEAD)      // 4608

typedef __attribute__((ext_vector_type(8))) short short8;
typedef __attribute__((ext_vector_type(4))) float floatx4;

// Static device scratch (f32 ABI: inputs/outputs are float32; bf16 copies are
// made on the fly for the MFMA GEMMs).
__device__ unsigned short g_Xb   [(size_t)NTOK  * HDIM];    //  5.9 MB bf16 X
__device__ float          g_qkv  [(size_t)NTOK  * QKV_N];   // 21   MB f32 qkv
__device__ unsigned short g_attn [(size_t)NTOK  * QCOLS];   //  8.4 MB bf16 attn out
__device__ unsigned short g_WqkvT[(size_t)QKV_N * HDIM];    // 29.5 MB bf16 Wqkv^T
__device__ unsigned short g_WoT  [(size_t)HDIM  * QCOLS];   // 23.6 MB bf16 Wo^T

__device__ __forceinline__ unsigned short f2b(float f) {
    __hip_bfloat16 h = __float2bfloat16(f);
    return *reinterpret_cast<unsigned short*>(&h);
}

// ---------------------------------------------------------------------------
// Fused transpose + f32->bf16 convert: in (K x N f32) -> out (N x K bf16).
// ---------------------------------------------------------------------------
__global__ __launch_bounds__(256) void transpose_cvt(
        const float* __restrict__ in, unsigned short* __restrict__ out,
        int K, int N) {
    int bk = blockIdx.x, bn = blockIdx.y;
    int t = threadIdx.x;
    __shared__ __align__(16) unsigned short T[64 * 72];
    #pragma unroll
    for (int i = 0; i < 4; ++i) {
        int c = i * 256 + t;          // 0..1023 float4 slots
        int r = c >> 4, cc = (c & 15) * 4;
        float4 v = *(const float4*)(in + (size_t)(bk * 64 + r) * N + bn * 64 + cc);
        T[r * 72 + cc + 0] = f2b(v.x);
        T[r * 72 + cc + 1] = f2b(v.y);
        T[r * 72 + cc + 2] = f2b(v.z);
        T[r * 72 + cc + 3] = f2b(v.w);
    }
    __syncthreads();
    #pragma unroll
    for (int i = 0; i < 2; ++i) {
        int c = i * 256 + t;
        int rn = c >> 3, kc = (c & 7) * 8;
        int4 vv;
        unsigned short* tp = (unsigned short*)&vv;
        #pragma unroll
        for (int j = 0; j < 8; ++j) tp[j] = T[(kc + j) * 72 + rn];
        *(int4*)(out + (size_t)(bn * 64 + rn) * K + bk * 64 + kc) = vv;
    }
}

// ---------------------------------------------------------------------------
// Elementwise f32 -> bf16 convert (for X).
// ---------------------------------------------------------------------------
__global__ __launch_bounds__(256) void cvt_bf16(
        const float* __restrict__ in, unsigned short* __restrict__ out, int n4) {
    int id = blockIdx.x * 256 + threadIdx.x;
    if (id >= n4) return;
    float4 v = *(const float4*)(in + (size_t)id * 4);
    ushort4 o;
    o.x = f2b(v.x); o.y = f2b(v.y); o.z = f2b(v.z); o.w = f2b(v.w);
    *(ushort4*)(out + (size_t)id * 4) = o;
}

// ---------------------------------------------------------------------------
// GEMM: C(MxN f32) = A(MxK bf16) * B(KxN), B supplied pre-transposed (NxK bf16).
// 64x64 tile / block, 4 waves, mfma_f32_16x16x32_bf16.
// ---------------------------------------------------------------------------
__global__ __launch_bounds__(256) void gemm_bf16_f32(
        const unsigned short* __restrict__ A, const unsigned short* __restrict__ Bt,
        float* __restrict__ C, int M, int N, int K) {
    int bm = blockIdx.x, bn = blockIdx.y;
    int t = threadIdx.x, lane = t & 63, wid = t >> 6;
    int m_quad = lane >> 4, m_low = lane & 15;
    __shared__ __align__(16) unsigned short As[64 * 72];
    __shared__ __align__(16) unsigned short Bs[64 * 72];
    floatx4 acc[4];
    #pragma unroll
    for (int i = 0; i < 4; ++i) acc[i] = (floatx4){0.f, 0.f, 0.f, 0.f};

    const unsigned short* Ablk = A + (size_t)(bm * 64) * K;
    const unsigned short* Bblk = Bt + (size_t)(bn * 64) * K;

    for (int k0 = 0; k0 < K; k0 += 64) {
        #pragma unroll
        for (int i = 0; i < 2; ++i) {
            int c = i * 256 + t;
            int r = c >> 3, kc = (c & 7) * 8;
            *(int4*)&As[r * 72 + kc] = *(const int4*)(Ablk + (size_t)r * K + k0 + kc);
            *(int4*)&Bs[r * 72 + kc] = *(const int4*)(Bblk + (size_t)r * K + k0 + kc);
        }
        __syncthreads();
        #pragma unroll
        for (int kk = 0; kk < 64; kk += 32) {
            short8 af = *(const short8*)&As[(wid * 16 + m_low) * 72 + kk + m_quad * 8];
            #pragma unroll
            for (int nt = 0; nt < 4; ++nt) {
                short8 bf = *(const short8*)&Bs[(nt * 16 + m_low) * 72 + kk + m_quad * 8];
                acc[nt] = __builtin_amdgcn_mfma_f32_16x16x32_bf16(af, bf, acc[nt], 0, 0, 0);
            }
        }
        __syncthreads();
    }
    #pragma unroll
    for (int nt = 0; nt < 4; ++nt) {
        #pragma unroll
        for (int r = 0; r < 4; ++r) {
            int row = bm * 64 + wid * 16 + m_quad * 4 + r;
            int col = bn * 64 + nt * 16 + m_low;
            C[(size_t)row * N + col] = acc[nt][r];
        }
    }
}

// ---------------------------------------------------------------------------
// RoPE in-place on f32 qkv (q heads and k heads). positions == row index.
// ---------------------------------------------------------------------------
__global__ __launch_bounds__(256) void rope_kernel(float* __restrict__ qkv) {
    int id = blockIdx.x * 256 + threadIdx.x;
    const int total = NTOK * (NH + NKV) * (DHEAD / 2);  // 1024*72*32
    if (id >= total) return;
    int n = id / ((NH + NKV) * 32);
    int r = id - n * ((NH + NKV) * 32);
    int h = r >> 5, d = r & 31;
    int col = (h < NH) ? (h * DHEAD + d) : (KOFF + (h - NH) * DHEAD + d);
    size_t base = (size_t)n * QKV_N + col;
    float x1 = qkv[base];
    float x2 = qkv[base + 32];
    // inv_freq = theta^(-d/32) = exp(-d * ln(150000)/32)
    float inv = expf(-(float)d * 0.3724497053f);
    float ang = (float)n * inv;
    float s, c;
    sincosf(ang, &s, &c);
    qkv[base]      = x1 * c - x2 * s;
    qkv[base + 32] = x2 * c + x1 * s;
}

// ---------------------------------------------------------------------------
// Sliding-window attention with sinks, f32 in, bf16 out (feeds GEMM2).
// One block per (token n, kv-head kh); 4 waves x 2 q-heads each.
// K/V window staged f32 in LDS (row stride 68 floats -> uniform bank spread).
// ---------------------------------------------------------------------------
__global__ __launch_bounds__(256) void attn_kernel(
        const float* __restrict__ qkv,
        const float* __restrict__ sinks,
        unsigned short* __restrict__ aout) {
    int n = blockIdx.x, kh = blockIdx.y;
    int t = threadIdx.x, lane = t & 63, wid = t >> 6;

    __shared__ __align__(16) float Ks[WIN * 68];
    __shared__ __align__(16) float Vs[WIN * 68];
    __shared__ __align__(16) float Qs[GQ * DHEAD];
    __shared__ float Ps[GQ * WIN];

    // stage K and V windows (clamped idx; invalid w masked later)
    #pragma unroll
    for (int i = 0; i < 8; ++i) {
        int c = i * 256 + t;            // 0..2047 float4 slots
        int w = c >> 4, dc = (c & 15) * 4;
        int idx = n - (WIN - 1) + w;
        idx = idx < 0 ? 0 : idx;
        *(float4*)&Ks[w * 68 + dc] =
            *(const float4*)(qkv + (size_t)idx * QKV_N + KOFF + kh * DHEAD + dc);
        *(float4*)&Vs[w * 68 + dc] =
            *(const float4*)(qkv + (size_t)idx * QKV_N + VOFF + kh * DHEAD + dc);
    }
    // stage Q
    if (t < 128) {
        int g = t >> 4, dc = (t & 15) * 4;
        *(float4*)&Qs[g * DHEAD + dc] =
            *(const float4*)(qkv + (size_t)n * QKV_N + (kh * GQ + g) * DHEAD + dc);
    }
    __syncthreads();

    #pragma unroll
    for (int hh = 0; hh < 2; ++hh) {
        int g = wid * 2 + hh;
        int h = kh * GQ + g;
        // ---- scores for window positions lane and lane+64
        float s0 = 0.f, s1 = 0.f;
        #pragma unroll
        for (int dc = 0; dc < DHEAD; dc += 4) {
            float4 ka = *(const float4*)&Ks[lane * 68 + dc];
            float4 kb = *(const float4*)&Ks[(lane + 64) * 68 + dc];
            float4 qa = *(const float4*)&Qs[g * DHEAD + dc];
            s0 = fmaf(ka.x, qa.x, s0); s0 = fmaf(ka.y, qa.y, s0);
            s0 = fmaf(ka.z, qa.z, s0); s0 = fmaf(ka.w, qa.w, s0);
            s1 = fmaf(kb.x, qa.x, s1); s1 = fmaf(kb.y, qa.y, s1);
            s1 = fmaf(kb.z, qa.z, s1); s1 = fmaf(kb.w, qa.w, s1);
        }
        s0 *= 0.125f;   // D^-0.5
        s1 *= 0.125f;
        bool v0 = (n - (WIN - 1) + lane) >= 0;
        bool v1 = (n - 63 + lane) >= 0;
        if (!v0) s0 = -INFINITY;
        if (!v1) s1 = -INFINITY;
        // ---- softmax with sink
        float m = fmaxf(s0, s1);
        #pragma unroll
        for (int off = 1; off < 64; off <<= 1) m = fmaxf(m, __shfl_xor(m, off));
        float sink = sinks[h];
        m = fmaxf(m, sink);
        float p0 = v0 ? __expf(s0 - m) : 0.f;
        float p1 = v1 ? __expf(s1 - m) : 0.f;
        float sum = p0 + p1;
        #pragma unroll
        for (int off = 1; off < 64; off <<= 1) sum += __shfl_xor(sum, off);
        float denom = sum + __expf(sink - m);
        Ps[g * WIN + lane] = p0;
        Ps[g * WIN + 64 + lane] = p1;
        __syncthreads();   // uniform across all waves
        // ---- PV: lane = wsub*16 + d4 ; accumulate float4 over window
        int wsub = lane >> 4, d4 = lane & 15;
        float ox = 0.f, oy = 0.f, oz = 0.f, ow = 0.f;
        #pragma unroll 4
        for (int w0 = 0; w0 < WIN; w0 += 4) {
            int w = w0 + wsub;
            float p = Ps[g * WIN + w];
            float4 vv = *(const float4*)&Vs[w * 68 + d4 * 4];
            ox = fmaf(p, vv.x, ox);
            oy = fmaf(p, vv.y, oy);
            oz = fmaf(p, vv.z, oz);
            ow = fmaf(p, vv.w, ow);
        }
        #pragma unroll
        for (int off = 16; off < 64; off <<= 1) {
            ox += __shfl_xor(ox, off);
            oy += __shfl_xor(oy, off);
            oz += __shfl_xor(oz, off);
            ow += __shfl_xor(ow, off);
        }
        if (wsub == 0) {
            float inv = 1.f / denom;
            union { ushort4 v; unsigned short u[4]; } o;
            o.u[0] = f2b(ox * inv);
            o.u[1] = f2b(oy * inv);
            o.u[2] = f2b(oz * inv);
            o.u[3] = f2b(ow * inv);
            *(ushort4*)&aout[(size_t)n * QCOLS + h * DHEAD + d4 * 4] = o.v;
        }
        __syncthreads();
    }
}

// ---------------------------------------------------------------------------
extern "C" void kernel_launch(void* const* d_in, const int* in_sizes, int n_in,
                              void* d_out, int out_size, void* d_ws, size_t ws_size,
                              hipStream_t stream) {
    const float* X     = (const float*)d_in[0];  // 1024x2880 f32
    const float* Wqkv  = (const float*)d_in[1];  // 2880x5120 f32
    const float* Wo    = (const float*)d_in[2];  // 4096x2880 f32
    const float* sinks = (const float*)d_in[3];  // 64 f32
    // d_in[4] = positions (arange) — row index used directly
    float* out = (float*)d_out;                  // 1024x2880 f32

    unsigned short *Xb = nullptr, *attn = nullptr, *WqkvT = nullptr, *WoT = nullptr;
    float *qkv = nullptr;
    hipGetSymbolAddress((void**)&Xb,    HIP_SYMBOL(g_Xb));
    hipGetSymbolAddress((void**)&qkv,   HIP_SYMBOL(g_qkv));
    hipGetSymbolAddress((void**)&attn,  HIP_SYMBOL(g_attn));
    hipGetSymbolAddress((void**)&WqkvT, HIP_SYMBOL(g_WqkvT));
    hipGetSymbolAddress((void**)&WoT,   HIP_SYMBOL(g_WoT));

    // Convert X to bf16; transpose+convert weights so GEMM operands are K-contiguous
    cvt_bf16<<<(NTOK * HDIM / 4 + 255) / 256, 256, 0, stream>>>(X, Xb, NTOK * HDIM / 4);
    transpose_cvt<<<dim3(HDIM / 64, QKV_N / 64), 256, 0, stream>>>(Wqkv, WqkvT, HDIM, QKV_N);
    transpose_cvt<<<dim3(QCOLS / 64, HDIM / 64), 256, 0, stream>>>(Wo, WoT, QCOLS, HDIM);

    // QKV projection: (1024x2880) @ (2880x5120) -> f32
    gemm_bf16_f32<<<dim3(NTOK / 64, QKV_N / 64), 256, 0, stream>>>(Xb, WqkvT, qkv, NTOK, QKV_N, HDIM);

    // RoPE in-place on q and k (f32)
    rope_kernel<<<(NTOK * (NH + NKV) * 32) / 256, 256, 0, stream>>>(qkv);

    // Sliding-window attention with sinks -> bf16 attn
    attn_kernel<<<dim3(NTOK, NKV), 256, 0, stream>>>(qkv, sinks, attn);

    // Output projection: (1024x4096) @ (4096x2880) -> f32 out
    gemm_bf16_f32<<<dim3(NTOK / 64, HDIM / 64), 256, 0, stream>>>(attn, WoT, out, NTOK, HDIM, QCOLS);
}

// Round 4
// 388.225 us; speedup vs baseline: 1.2017x; 1.2017x over previous
//
#include <hip/hip_runtime.h>
#include <hip/hip_bf16.h>

// Problem constants
#define HDIM   2880
#define NH     64
#define NKV    8
#define DHEAD  64
#define GQ     (NH / NKV)     // 8
#define WIN    128
#define NTOK   1024
#define QKV_N  ((NH + 2 * NKV) * DHEAD)   // 5120
#define QCOLS  (NH * DHEAD)               // 4096
#define KOFF   QCOLS                      // 4096
#define VOFF   (QCOLS + NKV * DHEAD)      // 4608
#define WO_PAD 2944                       // 2880 padded to 23*128

typedef __attribute__((ext_vector_type(8))) short short8;
typedef __attribute__((ext_vector_type(4))) float floatx4;

// Static device scratch (zero-initialized at module load; harness only
// poisons d_ws/d_out). WoT padded rows [2880,2944) stay zero forever.
__device__ unsigned short g_Xb   [(size_t)NTOK  * HDIM];     //  5.9 MB bf16 X
__device__ float          g_qkv  [(size_t)NTOK  * QKV_N];    // 21   MB f32 qkv
__device__ unsigned short g_attn [(size_t)NTOK  * QCOLS];    //  8.4 MB bf16 attn out
__device__ unsigned short g_WqkvT[(size_t)QKV_N * HDIM];     // 29.5 MB bf16 Wqkv^T
__device__ unsigned short g_WoT  [(size_t)WO_PAD * QCOLS];   // 24.1 MB bf16 Wo^T (padded)

__device__ __forceinline__ unsigned short f2b(float f) {
    __hip_bfloat16 h = __float2bfloat16(f);
    return *reinterpret_cast<unsigned short*>(&h);
}

__device__ __forceinline__ void gload_lds16(const unsigned short* g, unsigned short* l) {
    __builtin_amdgcn_global_load_lds(
        (const __attribute__((address_space(1))) unsigned int*)g,
        (__attribute__((address_space(3))) unsigned int*)l, 16, 0, 0);
}

// ---------------------------------------------------------------------------
// Fused transpose + f32->bf16 convert: in (K x N f32) -> out (N x K bf16).
// ---------------------------------------------------------------------------
__global__ __launch_bounds__(256) void transpose_cvt(
        const float* __restrict__ in, unsigned short* __restrict__ out,
        int K, int N) {
    int bk = blockIdx.x, bn = blockIdx.y;
    int t = threadIdx.x;
    __shared__ __align__(16) unsigned short T[64 * 72];
    #pragma unroll
    for (int i = 0; i < 4; ++i) {
        int c = i * 256 + t;          // 0..1023 float4 slots
        int r = c >> 4, cc = (c & 15) * 4;
        float4 v = *(const float4*)(in + (size_t)(bk * 64 + r) * N + bn * 64 + cc);
        T[r * 72 + cc + 0] = f2b(v.x);
        T[r * 72 + cc + 1] = f2b(v.y);
        T[r * 72 + cc + 2] = f2b(v.z);
        T[r * 72 + cc + 3] = f2b(v.w);
    }
    __syncthreads();
    #pragma unroll
    for (int i = 0; i < 2; ++i) {
        int c = i * 256 + t;
        int rn = c >> 3, kc = (c & 7) * 8;
        int4 vv;
        unsigned short* tp = (unsigned short*)&vv;
        #pragma unroll
        for (int j = 0; j < 8; ++j) tp[j] = T[(kc + j) * 72 + rn];
        *(int4*)(out + (size_t)(bn * 64 + rn) * K + bk * 64 + kc) = vv;
    }
}

// ---------------------------------------------------------------------------
// Elementwise f32 -> bf16 convert (for X).
// ---------------------------------------------------------------------------
__global__ __launch_bounds__(256) void cvt_bf16(
        const float* __restrict__ in, unsigned short* __restrict__ out, int n4) {
    int id = blockIdx.x * 256 + threadIdx.x;
    if (id >= n4) return;
    float4 v = *(const float4*)(in + (size_t)id * 4);
    ushort4 o;
    o.x = f2b(v.x); o.y = f2b(v.y); o.z = f2b(v.z); o.w = f2b(v.w);
    *(ushort4*)(out + (size_t)id * 4) = o;
}

// ---------------------------------------------------------------------------
// m97-style GEMM: C(MxN f32) = A(MxK bf16) * Bt(NxK bf16)^T.
// 128x128 tile, BK=64, 4 waves (2x2), 4x4 MFMA tiles/wave, global_load_lds.
// Bt may have padded rows; C stores guarded by col < N.
// ---------------------------------------------------------------------------
__global__ __launch_bounds__(256) void gemm128(
        const unsigned short* __restrict__ A, const unsigned short* __restrict__ Bt,
        float* __restrict__ C, int M, int N, int K) {
    int bm = blockIdx.x, bn = blockIdx.y;
    int t = threadIdx.x, lane = t & 63, wid = t >> 6;
    int quad = lane >> 4, ml = lane & 15;
    int wm = wid >> 1, wn = wid & 1;
    __shared__ __align__(16) unsigned short As[128 * 64];
    __shared__ __align__(16) unsigned short Bs[128 * 64];
    floatx4 acc[4][4];
    #pragma unroll
    for (int i = 0; i < 4; ++i)
        #pragma unroll
        for (int j = 0; j < 4; ++j) acc[i][j] = (floatx4){0.f, 0.f, 0.f, 0.f};

    int srow = lane >> 3;            // 0..7 within an 8-row group
    int scol = (lane & 7) * 8;       // 0..56
    const unsigned short* Ab = A  + (size_t)(bm * 128) * K;
    const unsigned short* Bb = Bt + (size_t)(bn * 128) * K;

    for (int k0 = 0; k0 < K; k0 += 64) {
        #pragma unroll
        for (int j = 0; j < 4; ++j) {
            int grp = wid * 4 + j;               // 0..15: 8-row group
            int r = grp * 8 + srow;              // 0..127
            gload_lds16(Ab + (size_t)r * K + k0 + scol, &As[grp * 512]);
            gload_lds16(Bb + (size_t)r * K + k0 + scol, &Bs[grp * 512]);
        }
        __syncthreads();
        #pragma unroll
        for (int kk = 0; kk < 64; kk += 32) {
            short8 af[4], bf[4];
            #pragma unroll
            for (int mt = 0; mt < 4; ++mt)
                af[mt] = *(const short8*)&As[(wm * 64 + mt * 16 + ml) * 64 + kk + quad * 8];
            #pragma unroll
            for (int nt = 0; nt < 4; ++nt)
                bf[nt] = *(const short8*)&Bs[(wn * 64 + nt * 16 + ml) * 64 + kk + quad * 8];
            #pragma unroll
            for (int mt = 0; mt < 4; ++mt)
                #pragma unroll
                for (int nt = 0; nt < 4; ++nt)
                    acc[mt][nt] = __builtin_amdgcn_mfma_f32_16x16x32_bf16(af[mt], bf[nt], acc[mt][nt], 0, 0, 0);
        }
        __syncthreads();
    }
    #pragma unroll
    for (int mt = 0; mt < 4; ++mt)
        #pragma unroll
        for (int nt = 0; nt < 4; ++nt)
            #pragma unroll
            for (int r = 0; r < 4; ++r) {
                int row = bm * 128 + wm * 64 + mt * 16 + quad * 4 + r;
                int col = bn * 128 + wn * 64 + nt * 16 + ml;
                if (col < N) C[(size_t)row * N + col] = acc[mt][nt][r];
            }
}

// ---------------------------------------------------------------------------
// RoPE in-place on f32 qkv (q heads and k heads). positions == row index.
// ---------------------------------------------------------------------------
__global__ __launch_bounds__(256) void rope_kernel(float* __restrict__ qkv) {
    int id = blockIdx.x * 256 + threadIdx.x;
    const int total = NTOK * (NH + NKV) * (DHEAD / 2);
    if (id >= total) return;
    int n = id / ((NH + NKV) * 32);
    int r = id - n * ((NH + NKV) * 32);
    int h = r >> 5, d = r & 31;
    int col = (h < NH) ? (h * DHEAD + d) : (KOFF + (h - NH) * DHEAD + d);
    size_t base = (size_t)n * QKV_N + col;
    float x1 = qkv[base];
    float x2 = qkv[base + 32];
    float inv = expf(-(float)d * 0.3724497053f);   // theta^(-d/32)
    float ang = (float)n * inv;
    float s, c;
    sincosf(ang, &s, &c);
    qkv[base]      = x1 * c - x2 * s;
    qkv[base + 32] = x2 * c + x1 * s;
}

// ---------------------------------------------------------------------------
// MFMA flash-style sliding-window attention with sinks.
// Block = (32-token Q-tile, kv-head). 256 thr = 4 waves; M = 8 heads x 32 tok
// = 256 rows (m = g*32 + tl), wave w owns rows [w*64, w*64+64).
// K window rows [t0-127, t0+32] staged bf16; V staged transposed.
// ---------------------------------------------------------------------------
#define TQ     32
#define WROWS  160
#define KS_LD  72
#define VT_LD  168
#define PS_LD  168

__global__ __launch_bounds__(256) void attn_mfma(
        const float* __restrict__ qkv,
        const float* __restrict__ sinks,
        unsigned short* __restrict__ aout) {
    int t0 = blockIdx.x * TQ, kh = blockIdx.y;
    int t = threadIdx.x, lane = t & 63, wid = t >> 6;
    int quad = lane >> 4, ml = lane & 15;
    int wavebase = wid * 64;

    __shared__ __align__(16) unsigned short Ks[WROWS * KS_LD];   // 22.5 KB
    __shared__ __align__(16) unsigned short Vt[DHEAD * VT_LD];   // 21   KB
    __shared__ __align__(16) unsigned short Ps[256 * PS_LD];     // 84   KB

    // ---- stage K (row-major) and V (transposed), f32 -> bf16
    #pragma unroll
    for (int i = 0; i < 10; ++i) {
        int c = i * 256 + t;              // 0..2559
        int w = c >> 4, dc = (c & 15) * 4;
        int r = t0 - 127 + w;
        r = min(max(r, 0), NTOK - 1);
        const float* kp = qkv + (size_t)r * QKV_N + KOFF + kh * DHEAD + dc;
        float4 kv = *(const float4*)kp;
        ushort4 kb;
        kb.x = f2b(kv.x); kb.y = f2b(kv.y); kb.z = f2b(kv.z); kb.w = f2b(kv.w);
        *(ushort4*)&Ks[w * KS_LD + dc] = kb;
        const float* vp = qkv + (size_t)r * QKV_N + VOFF + kh * DHEAD + dc;
        float4 vv = *(const float4*)vp;
        Vt[(dc + 0) * VT_LD + w] = f2b(vv.x);
        Vt[(dc + 1) * VT_LD + w] = f2b(vv.y);
        Vt[(dc + 2) * VT_LD + w] = f2b(vv.z);
        Vt[(dc + 3) * VT_LD + w] = f2b(vv.w);
    }
    __syncthreads();

    // ---- Q A-fragments straight from global (f32 -> bf16), reused over nt
    short8 qf[4][2];
    #pragma unroll
    for (int mt = 0; mt < 4; ++mt) {
        int m = wavebase + mt * 16 + ml;
        int tl = m & 31, g = m >> 5;
        const float* qp = qkv + (size_t)(t0 + tl) * QKV_N + (kh * GQ + g) * DHEAD;
        #pragma unroll
        for (int kk = 0; kk < 2; ++kk) {
            float4 a = *(const float4*)(qp + kk * 32 + quad * 8);
            float4 b = *(const float4*)(qp + kk * 32 + quad * 8 + 4);
            union { short8 s; unsigned short u[8]; } pk;
            pk.u[0] = f2b(a.x); pk.u[1] = f2b(a.y); pk.u[2] = f2b(a.z); pk.u[3] = f2b(a.w);
            pk.u[4] = f2b(b.x); pk.u[5] = f2b(b.y); pk.u[6] = f2b(b.z); pk.u[7] = f2b(b.w);
            qf[mt][kk] = pk.s;
        }
    }

    // ---- S = Q K^T  (M=256 per block; this wave: 4 m-tiles x 10 n-tiles)
    floatx4 S[4][10];
    #pragma unroll
    for (int mt = 0; mt < 4; ++mt)
        #pragma unroll
        for (int nt = 0; nt < 10; ++nt) S[mt][nt] = (floatx4){0.f, 0.f, 0.f, 0.f};
    #pragma unroll
    for (int kk = 0; kk < 2; ++kk) {
        #pragma unroll
        for (int nt = 0; nt < 10; ++nt) {
            short8 kb = *(const short8*)&Ks[(nt * 16 + ml) * KS_LD + kk * 32 + quad * 8];
            #pragma unroll
            for (int mt = 0; mt < 4; ++mt)
                S[mt][nt] = __builtin_amdgcn_mfma_f32_16x16x32_bf16(qf[mt][kk], kb, S[mt][nt], 0, 0, 0);
        }
    }

    // ---- band mask + scale   (valid: w>=tl, w<=tl+127, w>=127-t0)
    int wmin0 = 127 - t0;
    #pragma unroll
    for (int mt = 0; mt < 4; ++mt) {
        #pragma unroll
        for (int r = 0; r < 4; ++r) {
            int tl = (wavebase + mt * 16 + quad * 4 + r) & 31;
            int wlo = tl > wmin0 ? tl : wmin0;
            int whi = tl + 127;
            #pragma unroll
            for (int nt = 0; nt < 10; ++nt) {
                int w = nt * 16 + ml;
                float s = S[mt][nt][r] * 0.125f;
                S[mt][nt][r] = (w >= wlo && w <= whi) ? s : -INFINITY;
            }
        }
    }

    // ---- softmax with sink (rows spread over 16 lanes of the quad)
    #pragma unroll
    for (int mt = 0; mt < 4; ++mt) {
        int g = (wavebase + mt * 16) >> 5;
        float sk = sinks[kh * GQ + g];
        #pragma unroll
        for (int r = 0; r < 4; ++r) {
            float rm = -INFINITY;
            #pragma unroll
            for (int nt = 0; nt < 10; ++nt) rm = fmaxf(rm, S[mt][nt][r]);
            #pragma unroll
            for (int off = 1; off < 16; off <<= 1) rm = fmaxf(rm, __shfl_xor(rm, off));
            rm = fmaxf(rm, sk);
            float sum = 0.f;
            #pragma unroll
            for (int nt = 0; nt < 10; ++nt) {
                float p = __expf(S[mt][nt][r] - rm);   // exp(-inf)=0 masks
                S[mt][nt][r] = p;
                sum += p;
            }
            #pragma unroll
            for (int off = 1; off < 16; off <<= 1) sum += __shfl_xor(sum, off);
            float inv = 1.f / (sum + __expf(sk - rm));
            #pragma unroll
            for (int nt = 0; nt < 10; ++nt) S[mt][nt][r] *= inv;
        }
    }

    // ---- store P~ (already /denom) to per-wave LDS region, bf16
    #pragma unroll
    for (int mt = 0; mt < 4; ++mt)
        #pragma unroll
        for (int r = 0; r < 4; ++r) {
            int m = wavebase + mt * 16 + quad * 4 + r;
            #pragma unroll
            for (int nt = 0; nt < 10; ++nt)
                Ps[m * PS_LD + nt * 16 + ml] = f2b(S[mt][nt][r]);
        }
    // per-wave region: no block barrier needed (compiler orders LDS RAW)

    // ---- O = P~ V   (K-dim = 160 = 5 x 32)
    floatx4 O[4][4];
    #pragma unroll
    for (int i = 0; i < 4; ++i)
        #pragma unroll
        for (int j = 0; j < 4; ++j) O[i][j] = (floatx4){0.f, 0.f, 0.f, 0.f};
    #pragma unroll
    for (int ks = 0; ks < 5; ++ks) {
        short8 pf[4];
        #pragma unroll
        for (int mt = 0; mt < 4; ++mt)
            pf[mt] = *(const short8*)&Ps[(wavebase + mt * 16 + ml) * PS_LD + ks * 32 + quad * 8];
        #pragma unroll
        for (int nt = 0; nt < 4; ++nt) {
            short8 vf = *(const short8*)&Vt[(nt * 16 + ml) * VT_LD + ks * 32 + quad * 8];
            #pragma unroll
            for (int mt = 0; mt < 4; ++mt)
                O[mt][nt] = __builtin_amdgcn_mfma_f32_16x16x32_bf16(pf[mt], vf, O[mt][nt], 0, 0, 0);
        }
    }

    // ---- write out (bf16), C-layout: col = nt*16+ml (=d), row = quad*4+r
    #pragma unroll
    for (int mt = 0; mt < 4; ++mt)
        #pragma unroll
        for (int r = 0; r < 4; ++r) {
            int m = wavebase + mt * 16 + quad * 4 + r;
            int tl = m & 31, g = m >> 5;
            unsigned short* op = aout + (size_t)(t0 + tl) * QCOLS + (kh * GQ + g) * DHEAD;
            #pragma unroll
            for (int nt = 0; nt < 4; ++nt)
                op[nt * 16 + ml] = f2b(O[mt][nt][r]);
        }
}

// ---------------------------------------------------------------------------
extern "C" void kernel_launch(void* const* d_in, const int* in_sizes, int n_in,
                              void* d_out, int out_size, void* d_ws, size_t ws_size,
                              hipStream_t stream) {
    const float* X     = (const float*)d_in[0];  // 1024x2880 f32
    const float* Wqkv  = (const float*)d_in[1];  // 2880x5120 f32
    const float* Wo    = (const float*)d_in[2];  // 4096x2880 f32
    const float* sinks = (const float*)d_in[3];  // 64 f32
    float* out = (float*)d_out;                  // 1024x2880 f32

    unsigned short *Xb = nullptr, *attn = nullptr, *WqkvT = nullptr, *WoT = nullptr;
    float *qkv = nullptr;
    hipGetSymbolAddress((void**)&Xb,    HIP_SYMBOL(g_Xb));
    hipGetSymbolAddress((void**)&qkv,   HIP_SYMBOL(g_qkv));
    hipGetSymbolAddress((void**)&attn,  HIP_SYMBOL(g_attn));
    hipGetSymbolAddress((void**)&WqkvT, HIP_SYMBOL(g_WqkvT));
    hipGetSymbolAddress((void**)&WoT,   HIP_SYMBOL(g_WoT));

    cvt_bf16<<<(NTOK * HDIM / 4 + 255) / 256, 256, 0, stream>>>(X, Xb, NTOK * HDIM / 4);
    transpose_cvt<<<dim3(HDIM / 64, QKV_N / 64), 256, 0, stream>>>(Wqkv, WqkvT, HDIM, QKV_N);
    transpose_cvt<<<dim3(QCOLS / 64, HDIM / 64), 256, 0, stream>>>(Wo, WoT, QCOLS, HDIM);

    // QKV projection: (1024x2880) @ (2880x5120) -> f32
    gemm128<<<dim3(NTOK / 128, QKV_N / 128), 256, 0, stream>>>(Xb, WqkvT, qkv, NTOK, QKV_N, HDIM);

    // RoPE in-place (f32)
    rope_kernel<<<(NTOK * (NH + NKV) * 32) / 256, 256, 0, stream>>>(qkv);

    // MFMA sliding-window attention -> bf16 attn
    attn_mfma<<<dim3(NTOK / TQ, NKV), 256, 0, stream>>>(qkv, sinks, attn);

    // Output projection: (1024x4096) @ (4096x2880) -> f32 out (N padded tiles)
    gemm128<<<dim3(NTOK / 128, (HDIM + 127) / 128), 256, 0, stream>>>(attn, WoT, out, NTOK, HDIM, QCOLS);
}

// Round 5
// 348.496 us; speedup vs baseline: 1.3387x; 1.1140x over previous
//
#include <hip/hip_runtime.h>
#include <hip/hip_bf16.h>

// Problem constants
#define HDIM   2880
#define NH     64
#define NKV    8
#define DHEAD  64
#define GQ     (NH / NKV)     // 8
#define WIN    128
#define NTOK   1024
#define QKV_N  ((NH + 2 * NKV) * DHEAD)   // 5120
#define QCOLS  (NH * DHEAD)               // 4096
#define KOFF   QCOLS                      // 4096
#define VOFF   (QCOLS + NKV * DHEAD)      // 4608
#define WO_PAD 2944                       // 2880 padded to 23*128

typedef __attribute__((ext_vector_type(8))) short short8;
typedef __attribute__((ext_vector_type(4))) float floatx4;

// Static device scratch (zero-initialized at module load; harness only
// poisons d_ws/d_out). WoT padded rows [2880,2944) stay zero forever.
__device__ unsigned short g_Xb   [(size_t)NTOK  * HDIM];     //  5.9 MB bf16 X
__device__ float          g_qkv  [(size_t)NTOK  * QKV_N];    // 21   MB f32 qkv
__device__ unsigned short g_attn [(size_t)NTOK  * QCOLS];    //  8.4 MB bf16 attn out
__device__ unsigned short g_WqkvT[(size_t)QKV_N * HDIM];     // 29.5 MB bf16 Wqkv^T
__device__ unsigned short g_WoT  [(size_t)WO_PAD * QCOLS];   // 24.1 MB bf16 Wo^T (padded)

__device__ __forceinline__ unsigned short f2b(float f) {
    __hip_bfloat16 h = __float2bfloat16(f);
    return *reinterpret_cast<unsigned short*>(&h);
}

__device__ __forceinline__ void gload_lds16(const unsigned short* g, unsigned short* l) {
    __builtin_amdgcn_global_load_lds(
        (const __attribute__((address_space(1))) unsigned int*)g,
        (__attribute__((address_space(3))) unsigned int*)l, 16, 0, 0);
}

// ---------------------------------------------------------------------------
// Fused transpose + f32->bf16 convert: in (K x N f32) -> out (N x K bf16).
// ---------------------------------------------------------------------------
__global__ __launch_bounds__(256) void transpose_cvt(
        const float* __restrict__ in, unsigned short* __restrict__ out,
        int K, int N) {
    int bk = blockIdx.x, bn = blockIdx.y;
    int t = threadIdx.x;
    __shared__ __align__(16) unsigned short T[64 * 72];
    #pragma unroll
    for (int i = 0; i < 4; ++i) {
        int c = i * 256 + t;          // 0..1023 float4 slots
        int r = c >> 4, cc = (c & 15) * 4;
        float4 v = *(const float4*)(in + (size_t)(bk * 64 + r) * N + bn * 64 + cc);
        T[r * 72 + cc + 0] = f2b(v.x);
        T[r * 72 + cc + 1] = f2b(v.y);
        T[r * 72 + cc + 2] = f2b(v.z);
        T[r * 72 + cc + 3] = f2b(v.w);
    }
    __syncthreads();
    #pragma unroll
    for (int i = 0; i < 2; ++i) {
        int c = i * 256 + t;
        int rn = c >> 3, kc = (c & 7) * 8;
        int4 vv;
        unsigned short* tp = (unsigned short*)&vv;
        #pragma unroll
        for (int j = 0; j < 8; ++j) tp[j] = T[(kc + j) * 72 + rn];
        *(int4*)(out + (size_t)(bn * 64 + rn) * K + bk * 64 + kc) = vv;
    }
}

// ---------------------------------------------------------------------------
// Elementwise f32 -> bf16 convert (for X).
// ---------------------------------------------------------------------------
__global__ __launch_bounds__(256) void cvt_bf16(
        const float* __restrict__ in, unsigned short* __restrict__ out, int n4) {
    int id = blockIdx.x * 256 + threadIdx.x;
    if (id >= n4) return;
    float4 v = *(const float4*)(in + (size_t)id * 4);
    ushort4 o;
    o.x = f2b(v.x); o.y = f2b(v.y); o.z = f2b(v.z); o.w = f2b(v.w);
    *(ushort4*)(out + (size_t)id * 4) = o;
}

// ---------------------------------------------------------------------------
// GEMM: C(MxN f32) = A(MxK bf16) * Bt(NxK bf16)^T.
// 64x128 tile (M-tile 64 to raise grid parallelism at M=1024), BK=64,
// 4 waves (2x2), wave tile 32x64 = 2x4 MFMA tiles, global_load_lds staging.
// Bt may have padded rows; C stores guarded by col < N.
// ---------------------------------------------------------------------------
__global__ __launch_bounds__(256) void gemm64(
        const unsigned short* __restrict__ A, const unsigned short* __restrict__ Bt,
        float* __restrict__ C, int M, int N, int K) {
    int bm = blockIdx.x, bn = blockIdx.y;
    int t = threadIdx.x, lane = t & 63, wid = t >> 6;
    int quad = lane >> 4, ml = lane & 15;
    int wm = wid >> 1, wn = wid & 1;
    __shared__ __align__(16) unsigned short As[64 * 64];    //  8 KB
    __shared__ __align__(16) unsigned short Bs[128 * 64];   // 16 KB
    floatx4 acc[2][4];
    #pragma unroll
    for (int i = 0; i < 2; ++i)
        #pragma unroll
        for (int j = 0; j < 4; ++j) acc[i][j] = (floatx4){0.f, 0.f, 0.f, 0.f};

    int srow = lane >> 3;            // 0..7 within an 8-row group
    int scol = (lane & 7) * 8;       // 0..56
    const unsigned short* Ab = A  + (size_t)(bm * 64)  * K;
    const unsigned short* Bb = Bt + (size_t)(bn * 128) * K;

    for (int k0 = 0; k0 < K; k0 += 64) {
        #pragma unroll
        for (int j = 0; j < 2; ++j) {            // A: 8 groups of 8 rows
            int grp = wid * 2 + j;
            int r = grp * 8 + srow;
            gload_lds16(Ab + (size_t)r * K + k0 + scol, &As[grp * 512]);
        }
        #pragma unroll
        for (int j = 0; j < 4; ++j) {            // B: 16 groups of 8 rows
            int grp = wid * 4 + j;
            int r = grp * 8 + srow;
            gload_lds16(Bb + (size_t)r * K + k0 + scol, &Bs[grp * 512]);
        }
        __syncthreads();
        #pragma unroll
        for (int kk = 0; kk < 64; kk += 32) {
            short8 af[2], bf[4];
            #pragma unroll
            for (int mt = 0; mt < 2; ++mt)
                af[mt] = *(const short8*)&As[(wm * 32 + mt * 16 + ml) * 64 + kk + quad * 8];
            #pragma unroll
            for (int nt = 0; nt < 4; ++nt)
                bf[nt] = *(const short8*)&Bs[(wn * 64 + nt * 16 + ml) * 64 + kk + quad * 8];
            #pragma unroll
            for (int mt = 0; mt < 2; ++mt)
                #pragma unroll
                for (int nt = 0; nt < 4; ++nt)
                    acc[mt][nt] = __builtin_amdgcn_mfma_f32_16x16x32_bf16(af[mt], bf[nt], acc[mt][nt], 0, 0, 0);
        }
        __syncthreads();
    }
    #pragma unroll
    for (int mt = 0; mt < 2; ++mt)
        #pragma unroll
        for (int nt = 0; nt < 4; ++nt)
            #pragma unroll
            for (int r = 0; r < 4; ++r) {
                int row = bm * 64 + wm * 32 + mt * 16 + quad * 4 + r;
                int col = bn * 128 + wn * 64 + nt * 16 + ml;
                if (col < N) C[(size_t)row * N + col] = acc[mt][nt][r];
            }
}

// ---------------------------------------------------------------------------
// RoPE in-place on f32 qkv (q heads and k heads). positions == row index.
// ---------------------------------------------------------------------------
__global__ __launch_bounds__(256) void rope_kernel(float* __restrict__ qkv) {
    int id = blockIdx.x * 256 + threadIdx.x;
    const int total = NTOK * (NH + NKV) * (DHEAD / 2);
    if (id >= total) return;
    int n = id / ((NH + NKV) * 32);
    int r = id - n * ((NH + NKV) * 32);
    int h = r >> 5, d = r & 31;
    int col = (h < NH) ? (h * DHEAD + d) : (KOFF + (h - NH) * DHEAD + d);
    size_t base = (size_t)n * QKV_N + col;
    float x1 = qkv[base];
    float x2 = qkv[base + 32];
    float inv = expf(-(float)d * 0.3724497053f);   // theta^(-d/32)
    float ang = (float)n * inv;
    float s, c;
    sincosf(ang, &s, &c);
    qkv[base]      = x1 * c - x2 * s;
    qkv[base + 32] = x2 * c + x1 * s;
}

// ---------------------------------------------------------------------------
// MFMA flash-style sliding-window attention with sinks.
// Block = (32-token Q-tile, kv-head). 256 thr = 4 waves; M = 8 heads x 32 tok
// = 256 rows (m = g*32 + tl), wave w owns rows [w*64, w*64+64).
// Ps shrunk to 16 rows/wave (PV one m-tile at a time): LDS 64.5 KB ->
// 2 blocks/CU (was 76.5 KB -> 1 block/CU).
// ---------------------------------------------------------------------------
#define TQ     32
#define WROWS  160
#define KS_LD  72
#define VT_LD  168
#define PS_LD  168

__global__ __launch_bounds__(256) void attn_mfma(
        const float* __restrict__ qkv,
        const float* __restrict__ sinks,
        unsigned short* __restrict__ aout) {
    int t0 = blockIdx.x * TQ, kh = blockIdx.y;
    int t = threadIdx.x, lane = t & 63, wid = t >> 6;
    int quad = lane >> 4, ml = lane & 15;
    int wavebase = wid * 64;

    __shared__ __align__(16) unsigned short Ks[WROWS * KS_LD];    // 22.5 KB
    __shared__ __align__(16) unsigned short Vt[DHEAD * VT_LD];    // 21   KB
    __shared__ __align__(16) unsigned short Ps[4 * 16 * PS_LD];   // 21   KB
    unsigned short* Psw = &Ps[wid * 16 * PS_LD];

    // ---- stage K (row-major) and V (transposed), f32 -> bf16
    #pragma unroll
    for (int i = 0; i < 10; ++i) {
        int c = i * 256 + t;              // 0..2559
        int w = c >> 4, dc = (c & 15) * 4;
        int r = t0 - 127 + w;
        r = min(max(r, 0), NTOK - 1);
        const float* kp = qkv + (size_t)r * QKV_N + KOFF + kh * DHEAD + dc;
        float4 kv = *(const float4*)kp;
        ushort4 kb;
        kb.x = f2b(kv.x); kb.y = f2b(kv.y); kb.z = f2b(kv.z); kb.w = f2b(kv.w);
        *(ushort4*)&Ks[w * KS_LD + dc] = kb;
        const float* vp = qkv + (size_t)r * QKV_N + VOFF + kh * DHEAD + dc;
        float4 vv = *(const float4*)vp;
        Vt[(dc + 0) * VT_LD + w] = f2b(vv.x);
        Vt[(dc + 1) * VT_LD + w] = f2b(vv.y);
        Vt[(dc + 2) * VT_LD + w] = f2b(vv.z);
        Vt[(dc + 3) * VT_LD + w] = f2b(vv.w);
    }
    __syncthreads();

    // ---- Q A-fragments straight from global (f32 -> bf16), reused over nt
    short8 qf[4][2];
    #pragma unroll
    for (int mt = 0; mt < 4; ++mt) {
        int m = wavebase + mt * 16 + ml;
        int tl = m & 31, g = m >> 5;
        const float* qp = qkv + (size_t)(t0 + tl) * QKV_N + (kh * GQ + g) * DHEAD;
        #pragma unroll
        for (int kk = 0; kk < 2; ++kk) {
            float4 a = *(const float4*)(qp + kk * 32 + quad * 8);
            float4 b = *(const float4*)(qp + kk * 32 + quad * 8 + 4);
            union { short8 s; unsigned short u[8]; } pk;
            pk.u[0] = f2b(a.x); pk.u[1] = f2b(a.y); pk.u[2] = f2b(a.z); pk.u[3] = f2b(a.w);
            pk.u[4] = f2b(b.x); pk.u[5] = f2b(b.y); pk.u[6] = f2b(b.z); pk.u[7] = f2b(b.w);
            qf[mt][kk] = pk.s;
        }
    }

    // ---- S = Q K^T  (this wave: 4 m-tiles x 10 n-tiles)
    floatx4 S[4][10];
    #pragma unroll
    for (int mt = 0; mt < 4; ++mt)
        #pragma unroll
        for (int nt = 0; nt < 10; ++nt) S[mt][nt] = (floatx4){0.f, 0.f, 0.f, 0.f};
    #pragma unroll
    for (int kk = 0; kk < 2; ++kk) {
        #pragma unroll
        for (int nt = 0; nt < 10; ++nt) {
            short8 kb = *(const short8*)&Ks[(nt * 16 + ml) * KS_LD + kk * 32 + quad * 8];
            #pragma unroll
            for (int mt = 0; mt < 4; ++mt)
                S[mt][nt] = __builtin_amdgcn_mfma_f32_16x16x32_bf16(qf[mt][kk], kb, S[mt][nt], 0, 0, 0);
        }
    }

    // ---- band mask + scale   (valid: w>=tl, w<=tl+127, w>=127-t0)
    int wmin0 = 127 - t0;
    #pragma unroll
    for (int mt = 0; mt < 4; ++mt) {
        #pragma unroll
        for (int r = 0; r < 4; ++r) {
            int tl = (wavebase + mt * 16 + quad * 4 + r) & 31;
            int wlo = tl > wmin0 ? tl : wmin0;
            int whi = tl + 127;
            #pragma unroll
            for (int nt = 0; nt < 10; ++nt) {
                int w = nt * 16 + ml;
                float s = S[mt][nt][r] * 0.125f;
                S[mt][nt][r] = (w >= wlo && w <= whi) ? s : -INFINITY;
            }
        }
    }

    // ---- softmax with sink (rows spread over 16 lanes of the quad)
    #pragma unroll
    for (int mt = 0; mt < 4; ++mt) {
        int g = (wavebase + mt * 16) >> 5;
        float sk = sinks[kh * GQ + g];
        #pragma unroll
        for (int r = 0; r < 4; ++r) {
            float rm = -INFINITY;
            #pragma unroll
            for (int nt = 0; nt < 10; ++nt) rm = fmaxf(rm, S[mt][nt][r]);
            #pragma unroll
            for (int off = 1; off < 16; off <<= 1) rm = fmaxf(rm, __shfl_xor(rm, off));
            rm = fmaxf(rm, sk);
            float sum = 0.f;
            #pragma unroll
            for (int nt = 0; nt < 10; ++nt) {
                float p = __expf(S[mt][nt][r] - rm);   // exp(-inf)=0 masks
                S[mt][nt][r] = p;
                sum += p;
            }
            #pragma unroll
            for (int off = 1; off < 16; off <<= 1) sum += __shfl_xor(sum, off);
            float inv = 1.f / (sum + __expf(sk - rm));
            #pragma unroll
            for (int nt = 0; nt < 10; ++nt) S[mt][nt][r] *= inv;
        }
    }

    // ---- PV one m-tile at a time through the 16-row per-wave Ps region.
    // DS ops from one wave execute in order, so write/read/rewrite of the
    // same region needs no barrier (per-wave region, no cross-wave sharing).
    #pragma unroll
    for (int mt = 0; mt < 4; ++mt) {
        int m = wavebase + mt * 16;
        #pragma unroll
        for (int r = 0; r < 4; ++r) {
            int lr = quad * 4 + r;
            #pragma unroll
            for (int nt = 0; nt < 10; ++nt)
                Psw[lr * PS_LD + nt * 16 + ml] = f2b(S[mt][nt][r]);
        }
        floatx4 O[4];
        #pragma unroll
        for (int j = 0; j < 4; ++j) O[j] = (floatx4){0.f, 0.f, 0.f, 0.f};
        #pragma unroll
        for (int ks = 0; ks < 5; ++ks) {
            short8 pf = *(const short8*)&Psw[ml * PS_LD + ks * 32 + quad * 8];
            #pragma unroll
            for (int nt = 0; nt < 4; ++nt) {
                short8 vf = *(const short8*)&Vt[(nt * 16 + ml) * VT_LD + ks * 32 + quad * 8];
                O[nt] = __builtin_amdgcn_mfma_f32_16x16x32_bf16(pf, vf, O[nt], 0, 0, 0);
            }
        }
        // write out (bf16): col = nt*16+ml (=d), row m + quad*4+r
        #pragma unroll
        for (int r = 0; r < 4; ++r) {
            int mm = m + quad * 4 + r;
            int tl = mm & 31, g = mm >> 5;
            unsigned short* op = aout + (size_t)(t0 + tl) * QCOLS + (kh * GQ + g) * DHEAD;
            #pragma unroll
            for (int nt = 0; nt < 4; ++nt)
                op[nt * 16 + ml] = f2b(O[nt][r]);
        }
    }
}

// ---------------------------------------------------------------------------
extern "C" void kernel_launch(void* const* d_in, const int* in_sizes, int n_in,
                              void* d_out, int out_size, void* d_ws, size_t ws_size,
                              hipStream_t stream) {
    const float* X     = (const float*)d_in[0];  // 1024x2880 f32
    const float* Wqkv  = (const float*)d_in[1];  // 2880x5120 f32
    const float* Wo    = (const float*)d_in[2];  // 4096x2880 f32
    const float* sinks = (const float*)d_in[3];  // 64 f32
    float* out = (float*)d_out;                  // 1024x2880 f32

    unsigned short *Xb = nullptr, *attn = nullptr, *WqkvT = nullptr, *WoT = nullptr;
    float *qkv = nullptr;
    hipGetSymbolAddress((void**)&Xb,    HIP_SYMBOL(g_Xb));
    hipGetSymbolAddress((void**)&qkv,   HIP_SYMBOL(g_qkv));
    hipGetSymbolAddress((void**)&attn,  HIP_SYMBOL(g_attn));
    hipGetSymbolAddress((void**)&WqkvT, HIP_SYMBOL(g_WqkvT));
    hipGetSymbolAddress((void**)&WoT,   HIP_SYMBOL(g_WoT));

    cvt_bf16<<<(NTOK * HDIM / 4 + 255) / 256, 256, 0, stream>>>(X, Xb, NTOK * HDIM / 4);
    transpose_cvt<<<dim3(HDIM / 64, QKV_N / 64), 256, 0, stream>>>(Wqkv, WqkvT, HDIM, QKV_N);
    transpose_cvt<<<dim3(QCOLS / 64, HDIM / 64), 256, 0, stream>>>(Wo, WoT, QCOLS, HDIM);

    // QKV projection: (1024x2880) @ (2880x5120) -> f32
    gemm64<<<dim3(NTOK / 64, QKV_N / 128), 256, 0, stream>>>(Xb, WqkvT, qkv, NTOK, QKV_N, HDIM);

    // RoPE in-place (f32)
    rope_kernel<<<(NTOK * (NH + NKV) * 32) / 256, 256, 0, stream>>>(qkv);

    // MFMA sliding-window attention -> bf16 attn
    attn_mfma<<<dim3(NTOK / TQ, NKV), 256, 0, stream>>>(qkv, sinks, attn);

    // Output projection: (1024x4096) @ (4096x2880) -> f32 out (N padded tiles)
    gemm64<<<dim3(NTOK / 64, WO_PAD / 128), 256, 0, stream>>>(attn, WoT, out, NTOK, HDIM, QCOLS);
}

// Round 7
// 333.024 us; speedup vs baseline: 1.4009x; 1.0465x over previous
//
#include <hip/hip_runtime.h>
#include <hip/hip_bf16.h>

// Problem constants
#define HDIM   2880
#define NH     64
#define NKV    8
#define DHEAD  64
#define GQ     (NH / NKV)     // 8
#define WIN    128
#define NTOK   1024
#define QKV_N  ((NH + 2 * NKV) * DHEAD)   // 5120
#define QCOLS  (NH * DHEAD)               // 4096
#define KOFF   QCOLS                      // 4096
#define VOFF   (QCOLS + NKV * DHEAD)      // 4608
#define WO_PAD 2944                       // 2880 padded to 23*128
#define SK1    3                          // split-K for qkv gemm (2880 = 3*960)
#define SK2    4                          // split-K for out gemm (4096 = 4*1024)

typedef __attribute__((ext_vector_type(8))) short short8;
typedef __attribute__((ext_vector_type(4))) float floatx4;

// Static device scratch (zero-init at module load; WoT pad rows stay zero).
__device__ unsigned short g_Xb   [(size_t)NTOK  * HDIM];          //  5.9 MB
__device__ unsigned short g_qkvb [(size_t)NTOK  * QKV_N];         // 10.5 MB bf16 qkv (post-rope)
__device__ unsigned short g_attn [(size_t)NTOK  * QCOLS];         //  8.4 MB
__device__ unsigned short g_WqkvT[(size_t)QKV_N * HDIM];          // 29.5 MB
__device__ unsigned short g_WoT  [(size_t)WO_PAD * QCOLS];        // 24.1 MB (padded)
__device__ float          g_part1[(size_t)SK1 * NTOK * QKV_N];    // 62.9 MB f32 partials
__device__ float          g_part2[(size_t)SK2 * NTOK * WO_PAD];   // 48.2 MB f32 partials

__device__ __forceinline__ unsigned short f2b(float f) {
    __hip_bfloat16 h = __float2bfloat16(f);
    return *reinterpret_cast<unsigned short*>(&h);
}

__device__ __forceinline__ void gload_lds16(const unsigned short* g, unsigned short* l) {
    __builtin_amdgcn_global_load_lds(
        (const __attribute__((address_space(1))) unsigned int*)g,
        (__attribute__((address_space(3))) unsigned int*)l, 16, 0, 0);
}

// ---------------------------------------------------------------------------
// Fused transpose + f32->bf16 convert: in (K x N f32) -> out (N x K bf16).
// ---------------------------------------------------------------------------
__global__ __launch_bounds__(256) void transpose_cvt(
        const float* __restrict__ in, unsigned short* __restrict__ out,
        int K, int N) {
    int bk = blockIdx.x, bn = blockIdx.y;
    int t = threadIdx.x;
    __shared__ __align__(16) unsigned short T[64 * 72];
    #pragma unroll
    for (int i = 0; i < 4; ++i) {
        int c = i * 256 + t;          // float4 slots
        int r = c >> 4, cc = (c & 15) * 4;
        float4 v = *(const float4*)(in + (size_t)(bk * 64 + r) * N + bn * 64 + cc);
        T[r * 72 + cc + 0] = f2b(v.x);
        T[r * 72 + cc + 1] = f2b(v.y);
        T[r * 72 + cc + 2] = f2b(v.z);
        T[r * 72 + cc + 3] = f2b(v.w);
    }
    __syncthreads();
    #pragma unroll
    for (int i = 0; i < 2; ++i) {
        int c = i * 256 + t;
        int rn = c >> 3, kc = (c & 7) * 8;
        int4 vv;
        unsigned short* tp = (unsigned short*)&vv;
        #pragma unroll
        for (int j = 0; j < 8; ++j) tp[j] = T[(kc + j) * 72 + rn];
        *(int4*)(out + (size_t)(bn * 64 + rn) * K + bk * 64 + kc) = vv;
    }
}

// ---------------------------------------------------------------------------
// Elementwise f32 -> bf16 convert (for X).
// ---------------------------------------------------------------------------
__global__ __launch_bounds__(256) void cvt_bf16(
        const float* __restrict__ in, unsigned short* __restrict__ out, int n4) {
    int id = blockIdx.x * 256 + threadIdx.x;
    if (id >= n4) return;
    float4 v = *(const float4*)(in + (size_t)id * 4);
    ushort4 o;
    o.x = f2b(v.x); o.y = f2b(v.y); o.z = f2b(v.z); o.w = f2b(v.w);
    *(ushort4*)(out + (size_t)id * 4) = o;
}

// ---------------------------------------------------------------------------
// Split-K GEMM: P[z] (Mx ldc f32) = A(MxK bf16) [k-chunk z] * Bt(ldc x K)^T.
// 128x128 tile, BK=64, 4 waves (2x2), 4x4 MFMA tiles/wave, global_load_lds.
// blockIdx.z selects the K-chunk; partials are summed by a reduce kernel.
// ---------------------------------------------------------------------------
__global__ __launch_bounds__(256) void gemm_sk(
        const unsigned short* __restrict__ A, const unsigned short* __restrict__ Bt,
        float* __restrict__ P, int K, int chunk, int ldc, size_t plane) {
    int bm = blockIdx.x, bn = blockIdx.y, z = blockIdx.z;
    int t = threadIdx.x, lane = t & 63, wid = t >> 6;
    int quad = lane >> 4, ml = lane & 15;
    int wm = wid >> 1, wn = wid & 1;
    __shared__ __align__(16) unsigned short As[128 * 64];
    __shared__ __align__(16) unsigned short Bs[128 * 64];
    floatx4 acc[4][4];
    #pragma unroll
    for (int i = 0; i < 4; ++i)
        #pragma unroll
        for (int j = 0; j < 4; ++j) acc[i][j] = (floatx4){0.f, 0.f, 0.f, 0.f};

    int srow = lane >> 3;            // 0..7 within an 8-row group
    int scol = (lane & 7) * 8;       // 0..56
    int base = z * chunk;
    const unsigned short* Ab = A  + (size_t)(bm * 128) * K + base;
    const unsigned short* Bb = Bt + (size_t)(bn * 128) * K + base;

    for (int k0 = 0; k0 < chunk; k0 += 64) {
        #pragma unroll
        for (int j = 0; j < 4; ++j) {
            int grp = wid * 4 + j;               // 0..15: 8-row group
            int r = grp * 8 + srow;              // 0..127
            gload_lds16(Ab + (size_t)r * K + k0 + scol, &As[grp * 512]);
            gload_lds16(Bb + (size_t)r * K + k0 + scol, &Bs[grp * 512]);
        }
        __syncthreads();
        #pragma unroll
        for (int kk = 0; kk < 64; kk += 32) {
            short8 af[4], bf[4];
            #pragma unroll
            for (int mt = 0; mt < 4; ++mt)
                af[mt] = *(const short8*)&As[(wm * 64 + mt * 16 + ml) * 64 + kk + quad * 8];
            #pragma unroll
            for (int nt = 0; nt < 4; ++nt)
                bf[nt] = *(const short8*)&Bs[(wn * 64 + nt * 16 + ml) * 64 + kk + quad * 8];
            #pragma unroll
            for (int mt = 0; mt < 4; ++mt)
                #pragma unroll
                for (int nt = 0; nt < 4; ++nt)
                    acc[mt][nt] = __builtin_amdgcn_mfma_f32_16x16x32_bf16(af[mt], bf[nt], acc[mt][nt], 0, 0, 0);
        }
        __syncthreads();
    }
    float* Cp = P + z * plane;
    #pragma unroll
    for (int mt = 0; mt < 4; ++mt)
        #pragma unroll
        for (int nt = 0; nt < 4; ++nt)
            #pragma unroll
            for (int r = 0; r < 4; ++r) {
                int row = bm * 128 + wm * 64 + mt * 16 + quad * 4 + r;
                int col = bn * 128 + wn * 64 + nt * 16 + ml;
                Cp[(size_t)row * ldc + col] = acc[mt][nt][r];
            }
}

// ---------------------------------------------------------------------------
// Reduce SK1 qkv partials + RoPE (f32) -> bf16 qkv. positions == row index.
// q/k units: (n, head hh<72, quad-of-4-dims q8<8); v units: (n, 4-dim slot).
// ---------------------------------------------------------------------------
#define QK_UNITS (NTOK * 72 * 8)   // 589824
#define V_UNITS  (NTOK * 128)      // 131072
__global__ __launch_bounds__(256) void reduce_rope(
        const float* __restrict__ P, unsigned short* __restrict__ qkvb) {
    int id = blockIdx.x * 256 + threadIdx.x;
    const size_t plane = (size_t)NTOK * QKV_N;
    if (id < QK_UNITS) {
        int n = id / 576;
        int rem = id - n * 576;
        int hh = rem >> 3, q8 = rem & 7;
        int c0 = (hh < NH) ? hh * 64 : KOFF + (hh - NH) * 64;
        size_t i1 = (size_t)n * QKV_N + c0 + q8 * 4;
        float4 a0 = *(const float4*)(P + i1);
        float4 a1 = *(const float4*)(P + plane + i1);
        float4 a2 = *(const float4*)(P + 2 * plane + i1);
        float4 b0 = *(const float4*)(P + i1 + 32);
        float4 b1 = *(const float4*)(P + plane + i1 + 32);
        float4 b2 = *(const float4*)(P + 2 * plane + i1 + 32);
        float x1[4] = {a0.x + a1.x + a2.x, a0.y + a1.y + a2.y,
                       a0.z + a1.z + a2.z, a0.w + a1.w + a2.w};
        float x2[4] = {b0.x + b1.x + b2.x, b0.y + b1.y + b2.y,
                       b0.z + b1.z + b2.z, b0.w + b1.w + b2.w};
        union { ushort4 v; unsigned short u[4]; } o1, o2;
        #pragma unroll
        for (int j = 0; j < 4; ++j) {
            int d = q8 * 4 + j;
            float inv = expf(-(float)d * 0.3724497053f);   // theta^(-d/32)
            float ang = (float)n * inv;
            float s, c;
            sincosf(ang, &s, &c);
            o1.u[j] = f2b(x1[j] * c - x2[j] * s);
            o2.u[j] = f2b(x2[j] * c + x1[j] * s);
        }
        *(ushort4*)(qkvb + i1) = o1.v;
        *(ushort4*)(qkvb + i1 + 32) = o2.v;
    } else if (id < QK_UNITS + V_UNITS) {
        int vid = id - QK_UNITS;
        int n = vid >> 7, s8 = vid & 127;
        size_t i1 = (size_t)n * QKV_N + VOFF + s8 * 4;
        float4 a0 = *(const float4*)(P + i1);
        float4 a1 = *(const float4*)(P + plane + i1);
        float4 a2 = *(const float4*)(P + 2 * plane + i1);
        union { ushort4 v; unsigned short u[4]; } o;
        o.u[0] = f2b(a0.x + a1.x + a2.x);
        o.u[1] = f2b(a0.y + a1.y + a2.y);
        o.u[2] = f2b(a0.z + a1.z + a2.z);
        o.u[3] = f2b(a0.w + a1.w + a2.w);
        *(ushort4*)(qkvb + i1) = o.v;
    }
}

// ---------------------------------------------------------------------------
// Reduce SK2 out-proj partials (padded ldc WO_PAD) -> f32 out (ld HDIM).
// ---------------------------------------------------------------------------
__global__ __launch_bounds__(256) void reduce_out(
        const float* __restrict__ P, float* __restrict__ out) {
    int id = blockIdx.x * 256 + threadIdx.x;
    if (id >= NTOK * (HDIM / 4)) return;
    int n = id / (HDIM / 4);
    int c = (id - n * (HDIM / 4)) * 4;
    const size_t plane = (size_t)NTOK * WO_PAD;
    size_t i = (size_t)n * WO_PAD + c;
    float4 a0 = *(const float4*)(P + i);
    float4 a1 = *(const float4*)(P + plane + i);
    float4 a2 = *(const float4*)(P + 2 * plane + i);
    float4 a3 = *(const float4*)(P + 3 * plane + i);
    float4 s;
    s.x = a0.x + a1.x + a2.x + a3.x;
    s.y = a0.y + a1.y + a2.y + a3.y;
    s.z = a0.z + a1.z + a2.z + a3.z;
    s.w = a0.w + a1.w + a2.w + a3.w;
    *(float4*)(out + (size_t)n * HDIM + c) = s;
}

// ---------------------------------------------------------------------------
// MFMA flash-style sliding-window attention with sinks, bf16 in/out.
// Block = (16-token Q-tile, kv-head) -> grid 64x8 = 512 blocks (2/CU).
// M = 8 heads x 16 tokens = 128 rows; wave w owns rows [w*32, w*32+32).
// Window rows [t0-127, t0+32] staged (>=143 used, rest clamped+masked).
// ---------------------------------------------------------------------------
#define TQ     16
#define WROWS  160
#define KS_LD  72
#define VT_LD  168
#define PS_LD  168

__global__ __launch_bounds__(256) void attn_mfma(
        const unsigned short* __restrict__ qkvb,
        const float* __restrict__ sinks,
        unsigned short* __restrict__ aout) {
    int t0 = blockIdx.x * TQ, kh = blockIdx.y;
    int t = threadIdx.x, lane = t & 63, wid = t >> 6;
    int quad = lane >> 4, ml = lane & 15;
    int wavebase = wid * 32;

    __shared__ __align__(16) unsigned short Ks[WROWS * KS_LD];    // 22.5 KB
    __shared__ __align__(16) unsigned short Vt[DHEAD * VT_LD];    // 21   KB
    __shared__ __align__(16) unsigned short Ps[4 * 16 * PS_LD];   // 21   KB
    unsigned short* Psw = &Ps[wid * 16 * PS_LD];

    // ---- stage K (row-major) and V (transposed), straight bf16 copies
    #pragma unroll
    for (int i = 0; i < 5; ++i) {
        int c = i * 256 + t;              // 0..1279 ushort8 slots
        int w = c >> 3, d8 = (c & 7) * 8;
        int r = t0 - 127 + w;
        r = min(max(r, 0), NTOK - 1);
        *(int4*)&Ks[w * KS_LD + d8] =
            *(const int4*)(qkvb + (size_t)r * QKV_N + KOFF + kh * DHEAD + d8);
        int4 vv = *(const int4*)(qkvb + (size_t)r * QKV_N + VOFF + kh * DHEAD + d8);
        const unsigned short* vp = (const unsigned short*)&vv;
        #pragma unroll
        for (int j = 0; j < 8; ++j) Vt[(d8 + j) * VT_LD + w] = vp[j];
    }
    __syncthreads();

    // ---- Q A-fragments straight from global bf16
    short8 qf[2][2];
    #pragma unroll
    for (int mt = 0; mt < 2; ++mt) {
        int m = wavebase + mt * 16 + ml;
        int tl = m & 15, g = m >> 4;
        const unsigned short* qp = qkvb + (size_t)(t0 + tl) * QKV_N + (kh * GQ + g) * DHEAD;
        #pragma unroll
        for (int kk = 0; kk < 2; ++kk)
            qf[mt][kk] = *(const short8*)(qp + kk * 32 + quad * 8);
    }

    // ---- S = Q K^T  (this wave: 2 m-tiles x 10 n-tiles)
    floatx4 S[2][10];
    #pragma unroll
    for (int mt = 0; mt < 2; ++mt)
        #pragma unroll
        for (int nt = 0; nt < 10; ++nt) S[mt][nt] = (floatx4){0.f, 0.f, 0.f, 0.f};
    #pragma unroll
    for (int kk = 0; kk < 2; ++kk) {
        #pragma unroll
        for (int nt = 0; nt < 10; ++nt) {
            short8 kb = *(const short8*)&Ks[(nt * 16 + ml) * KS_LD + kk * 32 + quad * 8];
            #pragma unroll
            for (int mt = 0; mt < 2; ++mt)
                S[mt][nt] = __builtin_amdgcn_mfma_f32_16x16x32_bf16(qf[mt][kk], kb, S[mt][nt], 0, 0, 0);
        }
    }

    // ---- band mask + scale   (valid: w>=tl, w<=tl+127, w>=127-t0)
    int wmin0 = 127 - t0;
    #pragma unroll
    for (int mt = 0; mt < 2; ++mt) {
        #pragma unroll
        for (int r = 0; r < 4; ++r) {
            int tl = (wavebase + mt * 16 + quad * 4 + r) & 15;
            int wlo = tl > wmin0 ? tl : wmin0;
            int whi = tl + 127;
            #pragma unroll
            for (int nt = 0; nt < 10; ++nt) {
                int w = nt * 16 + ml;
                float s = S[mt][nt][r] * 0.125f;
                S[mt][nt][r] = (w >= wlo && w <= whi) ? s : -INFINITY;
            }
        }
    }

    // ---- softmax with sink (rows spread over 16 lanes of the quad)
    #pragma unroll
    for (int mt = 0; mt < 2; ++mt) {
        int g = (wavebase + mt * 16) >> 4;
        float sk = sinks[kh * GQ + g];
        #pragma unroll
        for (int r = 0; r < 4; ++r) {
            float rm = -INFINITY;
            #pragma unroll
            for (int nt = 0; nt < 10; ++nt) rm = fmaxf(rm, S[mt][nt][r]);
            #pragma unroll
            for (int off = 1; off < 16; off <<= 1) rm = fmaxf(rm, __shfl_xor(rm, off));
            rm = fmaxf(rm, sk);
            float sum = 0.f;
            #pragma unroll
            for (int nt = 0; nt < 10; ++nt) {
                float p = __expf(S[mt][nt][r] - rm);   // exp(-inf)=0 masks
                S[mt][nt][r] = p;
                sum += p;
            }
            #pragma unroll
            for (int off = 1; off < 16; off <<= 1) sum += __shfl_xor(sum, off);
            float inv = 1.f / (sum + __expf(sk - rm));
            #pragma unroll
            for (int nt = 0; nt < 10; ++nt) S[mt][nt][r] *= inv;
        }
    }

    // ---- PV one m-tile at a time through per-wave Ps (wave DS ops in-order)
    #pragma unroll
    for (int mt = 0; mt < 2; ++mt) {
        #pragma unroll
        for (int r = 0; r < 4; ++r) {
            int lr = quad * 4 + r;
            #pragma unroll
            for (int nt = 0; nt < 10; ++nt)
                Psw[lr * PS_LD + nt * 16 + ml] = f2b(S[mt][nt][r]);
        }
        floatx4 O[4];
        #pragma unroll
        for (int j = 0; j < 4; ++j) O[j] = (floatx4){0.f, 0.f, 0.f, 0.f};
        #pragma unroll
        for (int ks = 0; ks < 5; ++ks) {
            short8 pf = *(const short8*)&Psw[ml * PS_LD + ks * 32 + quad * 8];
            #pragma unroll
            for (int nt = 0; nt < 4; ++nt) {
                short8 vf = *(const short8*)&Vt[(nt * 16 + ml) * VT_LD + ks * 32 + quad * 8];
                O[nt] = __builtin_amdgcn_mfma_f32_16x16x32_bf16(pf, vf, O[nt], 0, 0, 0);
            }
        }
        #pragma unroll
        for (int r = 0; r < 4; ++r) {
            int mm = wavebase + mt * 16 + quad * 4 + r;
            int tl = mm & 15, g = mm >> 4;
            unsigned short* op = aout + (size_t)(t0 + tl) * QCOLS + (kh * GQ + g) * DHEAD;
            #pragma unroll
            for (int nt = 0; nt < 4; ++nt)
                op[nt * 16 + ml] = f2b(O[nt][r]);
        }
    }
}

// ---------------------------------------------------------------------------
extern "C" void kernel_launch(void* const* d_in, const int* in_sizes, int n_in,
                              void* d_out, int out_size, void* d_ws, size_t ws_size,
                              hipStream_t stream) {
    const float* X     = (const float*)d_in[0];  // 1024x2880 f32
    const float* Wqkv  = (const float*)d_in[1];  // 2880x5120 f32
    const float* Wo    = (const float*)d_in[2];  // 4096x2880 f32
    const float* sinks = (const float*)d_in[3];  // 64 f32
    float* out = (float*)d_out;                  // 1024x2880 f32

    unsigned short *Xb, *qkvb, *attn, *WqkvT, *WoT;
    float *part1, *part2;
    hipGetSymbolAddress((void**)&Xb,    HIP_SYMBOL(g_Xb));
    hipGetSymbolAddress((void**)&qkvb,  HIP_SYMBOL(g_qkvb));
    hipGetSymbolAddress((void**)&attn,  HIP_SYMBOL(g_attn));
    hipGetSymbolAddress((void**)&WqkvT, HIP_SYMBOL(g_WqkvT));
    hipGetSymbolAddress((void**)&WoT,   HIP_SYMBOL(g_WoT));
    hipGetSymbolAddress((void**)&part1, HIP_SYMBOL(g_part1));
    hipGetSymbolAddress((void**)&part2, HIP_SYMBOL(g_part2));

    cvt_bf16<<<(NTOK * HDIM / 4 + 255) / 256, 256, 0, stream>>>(X, Xb, NTOK * HDIM / 4);
    transpose_cvt<<<dim3(HDIM / 64, QKV_N / 64), 256, 0, stream>>>(Wqkv, WqkvT, HDIM, QKV_N);
    transpose_cvt<<<dim3(QCOLS / 64, HDIM / 64), 256, 0, stream>>>(Wo, WoT, QCOLS, HDIM);

    // QKV projection with split-K=3 -> f32 partials
    gemm_sk<<<dim3(NTOK / 128, QKV_N / 128, SK1), 256, 0, stream>>>(
        Xb, WqkvT, part1, HDIM, HDIM / SK1, QKV_N, (size_t)NTOK * QKV_N);

    // Reduce partials + RoPE -> bf16 qkv
    reduce_rope<<<(QK_UNITS + V_UNITS) / 256, 256, 0, stream>>>(part1, qkvb);

    // MFMA sliding-window attention -> bf16 attn
    attn_mfma<<<dim3(NTOK / TQ, NKV), 256, 0, stream>>>(qkvb, sinks, attn);

    // Output projection with split-K=4 -> f32 partials (padded ldc)
    gemm_sk<<<dim3(NTOK / 128, WO_PAD / 128, SK2), 256, 0, stream>>>(
        attn, WoT, part2, QCOLS, QCOLS / SK2, WO_PAD, (size_t)NTOK * WO_PAD);

    // Reduce -> f32 out
    reduce_out<<<(NTOK * (HDIM / 4) + 255) / 256, 256, 0, stream>>>(part2, out);
}